// Round 4
// baseline (581.901 us; speedup 1.0000x reference)
//
#include <hip/hip_runtime.h>

#define BB 4
#define S 128
#define SS (S*S)
#define BSS (BB*SS)

__device__ __forceinline__ int off3(int b, int i, int j) { return (b * S + i) * S + j; }
__device__ __forceinline__ int off4(int b, int i, int j, int k) { return ((b * S + i) * S + j) * S + k; }

// ---------------------------------------------------------------------------
// q = sigmoid(src) + transposed copies. init: also base <- src.
// ws: qb[0], qe[1], qs[2], qbT[3], qeT[4], qsT[5], each BSS floats.
// ---------------------------------------------------------------------------
__global__ __launch_bounds__(128) void k_sigmoid(const float* __restrict__ sb,
                                                 const float* __restrict__ se,
                                                 const float* __restrict__ ss,
                                                 float* base,
                                                 float* __restrict__ ws, int init) {
    int bi = blockIdx.x;
    int b = bi >> 7, i = bi & (S - 1);
    int j = threadIdx.x;
    const float* src[3] = {sb, se, ss};
#pragma unroll
    for (int t = 0; t < 3; ++t) {
        float x = src[t][off3(b, i, j)];
        float q = 1.0f / (1.0f + expf(-x));
        ws[t * BSS + off3(b, i, j)] = q;
        ws[(3 + t) * BSS + off3(b, j, i)] = q;
        if (init) base[t * BSS + off3(b, i, j)] = x;
    }
}

// ---------------------------------------------------------------------------
// One einsum term per block; block streams ONE 64KB slab of ONE tensor.
// INNER LOOP IS PURE STREAM+VALU: per-lane register accumulators (16 per
// lane), NO shuffles / NO atomics until block end. The butterfly reduction
// runs once per block over all 16 accs (independent swizzles -> pipelined).
// grid = (128, 9, B). y<7: block (b, I=x) streams A[b,I,:,:], half-wave hw
// owns j = 8*jj+hw, lanes cover 4 k's (float4).
// y in {7,8}: gb/ge fused edge+span; block (b, Jt=x&15, Is=x>>4) streams
// A[b, I0..I0+15, 8Jt..8Jt+7, :]; half-wave owns J, lanes cover K.
// ---------------------------------------------------------------------------
__global__ __launch_bounds__(256) void k_terms(
    const float* __restrict__ be, const float* __restrict__ bb,
    const float* __restrict__ cb, const float* __restrict__ eb,
    const float* __restrict__ ee, const float* __restrict__ ce,
    const float* __restrict__ sp, const float* __restrict__ gb,
    const float* __restrict__ ge, const int* __restrict__ edge,
    const int* __restrict__ chart, const float* __restrict__ ws,
    float* __restrict__ base) {
    const int b = blockIdx.z, y = blockIdx.y, x = blockIdx.x;
    const int t = threadIdx.x, hw = t >> 5, lh = t & 31;
    const int K = 4 * lh;

    const float* qb = ws;
    const float* qe = ws + BSS;
    const float* qs = ws + 2 * BSS;
    const float* qbT = ws + 3 * BSS;
    const float* qeT = ws + 4 * BSS;
    const float* qsT = ws + 5 * BSS;

    if (y < 7) {
        const int I = x;
        const float* A;
        int plane;
        switch (y) {
            case 0: A = be; plane = 0; break;
            case 1: A = bb; plane = 0; break;
            case 2: A = cb; plane = 0; break;
            case 3: A = eb; plane = 1; break;
            case 4: A = ee; plane = 1; break;
            case 5: A = ce; plane = 1; break;
            default: A = sp; plane = 2; break;
        }
        const float* qrow = (y == 0 || y == 4) ? qe : (y == 1 || y == 3) ? qb : qs;
        const float4 coefI = *(const float4*)&qrow[off3(b, I, K)];
        const int4 ekv = *(const int4*)&edge[off3(b, I, K)];
        const int4 c0kv = *(const int4*)&chart[off3(b, 0, K)];
        const int Iprev = (I + S - 1) & (S - 1);
        bool ek[4], c0k[4];
#pragma unroll
        for (int c = 0; c < 4; ++c) {
            ek[c] = (&ekv.x)[c] != 0;
            c0k[c] = (&c0kv.x)[c] != 0;
        }

        float acc[16];
#pragma unroll
        for (int jj = 0; jj < 16; ++jj) acc[jj] = 0.f;

#pragma unroll
        for (int jj = 0; jj < 16; ++jj) {
            const int j = 8 * jj + hw;
            const float4 v = *(const float4*)&A[off4(b, I, j, K)];
            float4 coef = coefI;
            if (y == 2) coef = *(const float4*)&qbT[off3(b, j, K)];
            if (y == 5) coef = *(const float4*)&qeT[off3(b, j, K)];
            const bool e_ij = edge[off3(b, I, j)] != 0;
            const bool chIj = chart[off3(b, Iprev, j)] != 0;
            const bool c0j = chart[off3(b, 0, j)] != 0;
            const int mx = I > j ? I : j;
            const bool wkj = e_ij && (I != j);

            float a = 0.f;
#pragma unroll
            for (int c = 0; c < 4; ++c) {
                const int kc = K + c;
                bool m;
                if (y == 0) {
                    m = e_ij && ek[c] && (I != kc);
                } else if (y == 3) {
                    m = ek[c] && wkj;
                } else if (y == 6) {
                    m = chIj && (mx != kc) && c0j && c0k[c];
                } else {
                    m = e_ij && ek[c] && (I != kc) && (j != kc);
                }
                a += (m ? (&coef.x)[c] : 0.f) * (&v.x)[c];
            }
            acc[jj] = a;
        }

        // once-per-block butterfly: 16 independent swizzles per step
#pragma unroll
        for (int o = 16; o > 0; o >>= 1) {
#pragma unroll
            for (int jj = 0; jj < 16; ++jj) acc[jj] += __shfl_xor(acc[jj], o);
        }
        if (lh == 0) {
#pragma unroll
            for (int jj = 0; jj < 16; ++jj)
                atomicAdd(&base[plane * BSS + off3(b, I, 8 * jj + hw)], acc[jj]);
        }
    } else {
        const float* A = (y == 7) ? gb : ge;
        const float* qT = (y == 7) ? qbT : qeT;
        const int Jt = x & 15, Is = x >> 4;
        const int J = 8 * Jt + hw, I0 = 16 * Is;

        const float4 q_J = (y == 7) ? *(const float4*)&qs[off3(b, J, K)]
                                    : *(const float4*)&qsT[off3(b, J, K)];
        const int4 c0Kv = *(const int4*)&chart[off3(b, 0, K)];
        const bool c0J = chart[off3(b, 0, J)] != 0;
        const int Jprev = (J + S - 1) & (S - 1);
        const int4 chJKv = *(const int4*)&chart[off3(b, Jprev, K)];
        bool c0K[4], chJK[4], chKJ[4];
        int mxJ[4];
#pragma unroll
        for (int c = 0; c < 4; ++c) {
            c0K[c] = (&c0Kv.x)[c] != 0;
            chJK[c] = (&chJKv.x)[c] != 0;
            chKJ[c] = (y == 8) ? (chart[off3(b, (K + c + S - 1) & (S - 1), J)] != 0) : false;
            mxJ[c] = J > (K + c) ? J : (K + c);
        }

        float accE[16];
        float rs[4] = {0.f, 0.f, 0.f, 0.f};
#pragma unroll
        for (int s = 0; s < 16; ++s) accE[s] = 0.f;

#pragma unroll
        for (int s = 0; s < 16; ++s) {
            const int I = I0 + s;
            const float4 v = *(const float4*)&A[off4(b, I, J, K)];
            const int4 eIKv = *(const int4*)&edge[off3(b, I, K)];
            const bool eIJ = edge[off3(b, I, J)] != 0;
            const bool c0I = chart[off3(b, 0, I)] != 0;
            const float qT_JI = qT[off3(b, J, I)];

            float p = 0.f;
#pragma unroll
            for (int c = 0; c < 4; ++c) {
                const int Kc = K + c;
                const bool eIK = (&eIKv.x)[c] != 0;
                const float vv = (&v.x)[c];
                bool nc, o;
                if (y == 7) {
                    nc = eIJ && eIK && (I != Kc) && (J <= Kc) && (J >= I || Kc <= I);
                    o = !((J <= I) && (Kc >= I)) && chJK[c] && (mxJ[c] != I) && c0K[c] && c0I;
                } else {
                    nc = eIK && eIJ && (I != J) && (Kc <= J) && (Kc >= I || J <= I);
                    o = !((Kc <= I) && (J >= I)) && chKJ[c] && (mxJ[c] != I) && c0J && c0I;
                }
                p += (nc ? (&q_J.x)[c] : 0.f) * vv;
                rs[c] += (o ? qT_JI : 0.f) * vv;
            }
            accE[s] = p;
        }

#pragma unroll
        for (int o = 16; o > 0; o >>= 1) {
#pragma unroll
            for (int s = 0; s < 16; ++s) accE[s] += __shfl_xor(accE[s], o);
        }
        if (lh == 0) {
#pragma unroll
            for (int s = 0; s < 16; ++s)
                atomicAdd(&base[(y == 7 ? 0 : 1) * BSS + off3(b, I0 + s, J)], accE[s]);
        }

#pragma unroll
        for (int c = 0; c < 4; ++c) {
            if (y == 7)
                atomicAdd(&base[2 * BSS + off3(b, J, K + c)], rs[c]);
            else
                atomicAdd(&base[2 * BSS + off3(b, K + c, J)], rs[c]);
        }
    }
}

extern "C" void kernel_launch(void* const* d_in, const int* in_sizes, int n_in,
                              void* d_out, int out_size, void* d_ws, size_t ws_size,
                              hipStream_t stream) {
    (void)in_sizes; (void)n_in; (void)out_size; (void)ws_size;
    const float* s_const = (const float*)d_in[0];
    const float* s_arg_begin = (const float*)d_in[1];
    const float* s_arg_end = (const float*)d_in[2];
    const float* be = (const float*)d_in[3];
    const float* eb = (const float*)d_in[4];
    const float* bb = (const float*)d_in[5];
    const float* ee = (const float*)d_in[6];
    const float* cb = (const float*)d_in[7];
    const float* ce = (const float*)d_in[8];
    const float* gb = (const float*)d_in[9];
    const float* ge = (const float*)d_in[10];
    const float* sp = (const float*)d_in[11];
    const int* edge = (const int*)d_in[12];
    const int* chart = (const int*)d_in[13];
    float* base = (float*)d_out;
    float* ws = (float*)d_ws;

    for (int it = 0; it < 3; ++it) {
        if (it == 0)
            k_sigmoid<<<dim3(BB * S), dim3(S), 0, stream>>>(s_arg_begin, s_arg_end, s_const,
                                                            base, ws, 1);
        else
            k_sigmoid<<<dim3(BB * S), dim3(S), 0, stream>>>(base, base + BSS, base + 2 * BSS,
                                                            base, ws, 0);
        k_terms<<<dim3(S, 9, BB), dim3(256), 0, stream>>>(be, bb, cb, eb, ee, ce, sp, gb, ge,
                                                          edge, chart, ws, base);
    }
}

// Round 5
// 498.550 us; speedup vs baseline: 1.1672x; 1.1672x over previous
//
#include <hip/hip_runtime.h>

#define BB 4
#define S 128
#define SS (S*S)
#define BSS (BB*SS)

__device__ __forceinline__ int off3(int b, int i, int j) { return (b * S + i) * S + j; }
__device__ __forceinline__ int off4(int b, int i, int j, int k) { return ((b * S + i) * S + j) * S + k; }

// ---------------------------------------------------------------------------
// sigmoid + LDS-tiled transpose (coalesced stores both ways).
// ws planes: qb[0], qe[1], qs[2], qbT[3], qeT[4], qsT[5], each BSS floats.
// grid = (16 tiles, 3 planes, B). 256 thr: col=t&31, r0=t>>5, 4 rows/thread.
// ---------------------------------------------------------------------------
__global__ __launch_bounds__(256) void k_sigmoid(const float* __restrict__ sb,
                                                 const float* __restrict__ se,
                                                 const float* __restrict__ ss,
                                                 float* base,
                                                 float* __restrict__ ws, int init) {
    const int b = blockIdx.z, p = blockIdx.y;
    const int ti = blockIdx.x >> 2, tj = blockIdx.x & 3;
    const int col = threadIdx.x & 31, r0 = threadIdx.x >> 5;
    const float* src = (p == 0) ? sb : (p == 1) ? se : ss;

    __shared__ float tile[32][33];
#pragma unroll
    for (int rr = 0; rr < 4; ++rr) {
        const int row = r0 + 8 * rr;
        const int gi = 32 * ti + row, gj = 32 * tj + col;
        const float x = src[off3(b, gi, gj)];
        const float q = 1.0f / (1.0f + __expf(-x));
        ws[p * BSS + off3(b, gi, gj)] = q;
        if (init) base[p * BSS + off3(b, gi, gj)] = x;
        tile[row][col] = q;
    }
    __syncthreads();
#pragma unroll
    for (int rr = 0; rr < 4; ++rr) {
        const int rowo = r0 + 8 * rr;
        ws[(3 + p) * BSS + off3(b, 32 * tj + rowo, 32 * ti + col)] = tile[col][rowo];
    }
}

// ---------------------------------------------------------------------------
// One tensor slab per block, ONE load per inner iteration.
// grid = (128, 9, B). y<7: block (b,I=x) streams A[b,I,:,:]; per-j mask bits
// live in ballot-packed 64-bit registers; per-k coefficients pre-masked into
// pm[4]; diagonal exclusions (j==k / max(I,j)==k) are 4 per-lane compares.
// y=2/5 add one L1-resident float4 (qbT/qeT). y=7/8: gb/ge fused edge+span,
// ballot-ized eIJ / c0I. All reductions/atomics at block end only.
// ---------------------------------------------------------------------------
__global__ __launch_bounds__(256, 4) void k_terms(
    const float* __restrict__ be, const float* __restrict__ bb,
    const float* __restrict__ cb, const float* __restrict__ eb,
    const float* __restrict__ ee, const float* __restrict__ ce,
    const float* __restrict__ sp, const float* __restrict__ gb,
    const float* __restrict__ ge, const int* __restrict__ edge,
    const int* __restrict__ chart, const float* __restrict__ ws,
    float* __restrict__ base) {
    const int b = blockIdx.z, y = blockIdx.y, x = blockIdx.x;
    const int t = threadIdx.x, hw = t >> 5, lh = t & 31, l = t & 63;
    const int K = 4 * lh;

    const float* qb = ws;
    const float* qe = ws + BSS;
    const float* qs = ws + 2 * BSS;
    const float* qbT = ws + 3 * BSS;
    const float* qeT = ws + 4 * BSS;
    const float* qsT = ws + 5 * BSS;

    if (y < 7) {
        const int I = x;
        const float* A;
        int plane;
        switch (y) {
            case 0: A = be; plane = 0; break;
            case 1: A = bb; plane = 0; break;
            case 2: A = cb; plane = 0; break;
            case 3: A = eb; plane = 1; break;
            case 4: A = ee; plane = 1; break;
            case 5: A = ce; plane = 1; break;
            default: A = sp; plane = 2; break;
        }
        const int Iprev = (I + S - 1) & (S - 1);

        // ballot-packed per-j bits (wave-uniform)
        const bool pe0 = edge[off3(b, I, l)] != 0;
        const bool pe1 = edge[off3(b, I, 64 + l)] != 0;
        unsigned long long Mlo = __ballot(pe0), Mhi = __ballot(pe1);
        if (y == 6) {
            const bool pc0 = chart[off3(b, 0, l)] != 0;
            const bool pc1 = chart[off3(b, 0, 64 + l)] != 0;
            const bool ph0 = chart[off3(b, Iprev, l)] != 0;
            const bool ph1 = chart[off3(b, Iprev, 64 + l)] != 0;
            Mlo = __ballot(pc0) & __ballot(ph0);
            Mhi = __ballot(pc1) & __ballot(ph1);
        } else if (y == 3) {  // fold (I != j) into the bit row
            if (I < 64) Mlo &= ~(1ull << I);
            else Mhi &= ~(1ull << (I - 64));
        }

        // per-lane pre-masked coefficients
        const float* qrow = (y == 0 || y == 4) ? qe : (y == 1 || y == 3) ? qb : qs;
        const float4 qv = *(const float4*)&qrow[off3(b, I, K)];
        const int4 ekv = *(const int4*)&edge[off3(b, I, K)];
        const int4 c0kv = *(const int4*)&chart[off3(b, 0, K)];
        float pm[4];
        bool pmask[4];
#pragma unroll
        for (int c = 0; c < 4; ++c) {
            const bool ek = (&ekv.x)[c] != 0;
            const bool c0k = (&c0kv.x)[c] != 0;
            const bool nI = (I != K + c);
            if (y == 0 || y == 1 || y == 4) pm[c] = (ek && nI) ? (&qv.x)[c] : 0.f;
            else if (y == 3) pm[c] = ek ? (&qv.x)[c] : 0.f;
            else if (y == 6) pm[c] = c0k ? (&qv.x)[c] : 0.f;
            pmask[c] = ek && nI;  // for y 2/5
        }
        const int corrSel = (y == 1 || y == 4) ? 1 : (y == 6) ? 2 : 0;
        const float* qT3 = (y == 2) ? qbT : qeT;

        float acc[16];
        if (y == 2 || y == 5) {
#pragma unroll
            for (int jj = 0; jj < 16; ++jj) {
                const int j = 8 * jj + hw;
                const float4 v = *(const float4*)&A[off4(b, I, j, K)];
                const float4 cf = *(const float4*)&qT3[off3(b, j, K)];
                float dot = 0.f;
                float s[4];
#pragma unroll
                for (int c = 0; c < 4; ++c) {
                    s[c] = pmask[c] ? (&cf.x)[c] : 0.f;
                    dot += s[c] * (&v.x)[c];
                }
#pragma unroll
                for (int c = 0; c < 4; ++c)
                    dot -= (K + c == j) ? s[c] * (&v.x)[c] : 0.f;
                const unsigned long long M = (jj < 8) ? Mlo : Mhi;
                const bool bit = (M >> (((jj & 7) << 3) + hw)) & 1;
                acc[jj] = bit ? dot : 0.f;
            }
        } else {
#pragma unroll
            for (int jj = 0; jj < 16; ++jj) {
                const int j = 8 * jj + hw;
                const float4 v = *(const float4*)&A[off4(b, I, j, K)];
                float dot = pm[0] * v.x + pm[1] * v.y + pm[2] * v.z + pm[3] * v.w;
                const int ci = (corrSel == 0) ? 256 : (corrSel == 1) ? j : (I > j ? I : j);
#pragma unroll
                for (int c = 0; c < 4; ++c)
                    dot -= (K + c == ci) ? pm[c] * (&v.x)[c] : 0.f;
                const unsigned long long M = (jj < 8) ? Mlo : Mhi;
                const bool bit = (M >> (((jj & 7) << 3) + hw)) & 1;
                acc[jj] = bit ? dot : 0.f;
            }
        }

#pragma unroll
        for (int o = 16; o > 0; o >>= 1) {
#pragma unroll
            for (int jj = 0; jj < 16; ++jj) acc[jj] += __shfl_xor(acc[jj], o);
        }
        if (lh == 0) {
#pragma unroll
            for (int jj = 0; jj < 16; ++jj)
                atomicAdd(&base[plane * BSS + off3(b, I, 8 * jj + hw)], acc[jj]);
        }
    } else {
        const float* A = (y == 7) ? gb : ge;
        const float* qT = (y == 7) ? qbT : qeT;
        const int Jt = x & 15, Is = x >> 4;
        const int J = 8 * Jt + hw, I0 = 16 * Is;

        const float4 q_J = (y == 7) ? *(const float4*)&qs[off3(b, J, K)]
                                    : *(const float4*)&qsT[off3(b, J, K)];
        const int4 c0Kv = *(const int4*)&chart[off3(b, 0, K)];
        const bool c0J = chart[off3(b, 0, J)] != 0;
        const int Jprev = (J + S - 1) & (S - 1);
        const int4 chJKv = *(const int4*)&chart[off3(b, Jprev, K)];
        bool c0K[4], chJK[4], chKJ[4];
        int mxJ[4];
#pragma unroll
        for (int c = 0; c < 4; ++c) {
            c0K[c] = (&c0Kv.x)[c] != 0;
            chJK[c] = (&chJKv.x)[c] != 0;
            chKJ[c] = (y == 8) ? (chart[off3(b, (K + c + S - 1) & (S - 1), J)] != 0) : false;
            mxJ[c] = J > (K + c) ? J : (K + c);
        }

        // ballots: eIJ bits and c0I bits for I = I0..I0+15 (this lane's J)
        const unsigned long long MeIJ = __ballot(edge[off3(b, I0 + (l & 15), J)] != 0);
        const unsigned long long Mc0I = __ballot(chart[off3(b, 0, I0 + (l & 15))] != 0);
        const int hsh = l & 32;

        float accE[16];
        float rs[4] = {0.f, 0.f, 0.f, 0.f};

#pragma unroll
        for (int s = 0; s < 16; ++s) {
            const int I = I0 + s;
            const float4 v = *(const float4*)&A[off4(b, I, J, K)];
            const int4 eIKv = *(const int4*)&edge[off3(b, I, K)];
            const bool eIJ = (MeIJ >> (hsh + s)) & 1;
            const bool c0I = (Mc0I >> (hsh + s)) & 1;
            const float qT_JI = qT[off3(b, J, I)];

            float p = 0.f;
#pragma unroll
            for (int c = 0; c < 4; ++c) {
                const int Kc = K + c;
                const bool eIK = (&eIKv.x)[c] != 0;
                const float vv = (&v.x)[c];
                bool nc, o;
                if (y == 7) {
                    nc = eIJ && eIK && (I != Kc) && (J <= Kc) && (J >= I || Kc <= I);
                    o = !((J <= I) && (Kc >= I)) && chJK[c] && (mxJ[c] != I) && c0K[c] && c0I;
                } else {
                    nc = eIK && eIJ && (I != J) && (Kc <= J) && (Kc >= I || J <= I);
                    o = !((Kc <= I) && (J >= I)) && chKJ[c] && (mxJ[c] != I) && c0J && c0I;
                }
                p += (nc ? (&q_J.x)[c] : 0.f) * vv;
                rs[c] += (o ? qT_JI : 0.f) * vv;
            }
            accE[s] = p;
        }

#pragma unroll
        for (int o = 16; o > 0; o >>= 1) {
#pragma unroll
            for (int s = 0; s < 16; ++s) accE[s] += __shfl_xor(accE[s], o);
        }
        if (lh == 0) {
#pragma unroll
            for (int s = 0; s < 16; ++s)
                atomicAdd(&base[(y == 7 ? 0 : 1) * BSS + off3(b, I0 + s, J)], accE[s]);
        }

#pragma unroll
        for (int c = 0; c < 4; ++c) {
            if (y == 7)
                atomicAdd(&base[2 * BSS + off3(b, J, K + c)], rs[c]);
            else
                atomicAdd(&base[2 * BSS + off3(b, K + c, J)], rs[c]);
        }
    }
}

extern "C" void kernel_launch(void* const* d_in, const int* in_sizes, int n_in,
                              void* d_out, int out_size, void* d_ws, size_t ws_size,
                              hipStream_t stream) {
    (void)in_sizes; (void)n_in; (void)out_size; (void)ws_size;
    const float* s_const = (const float*)d_in[0];
    const float* s_arg_begin = (const float*)d_in[1];
    const float* s_arg_end = (const float*)d_in[2];
    const float* be = (const float*)d_in[3];
    const float* eb = (const float*)d_in[4];
    const float* bb = (const float*)d_in[5];
    const float* ee = (const float*)d_in[6];
    const float* cb = (const float*)d_in[7];
    const float* ce = (const float*)d_in[8];
    const float* gb = (const float*)d_in[9];
    const float* ge = (const float*)d_in[10];
    const float* sp = (const float*)d_in[11];
    const int* edge = (const int*)d_in[12];
    const int* chart = (const int*)d_in[13];
    float* base = (float*)d_out;
    float* ws = (float*)d_ws;

    for (int it = 0; it < 3; ++it) {
        if (it == 0)
            k_sigmoid<<<dim3(16, 3, BB), dim3(256), 0, stream>>>(s_arg_begin, s_arg_end,
                                                                 s_const, base, ws, 1);
        else
            k_sigmoid<<<dim3(16, 3, BB), dim3(256), 0, stream>>>(base, base + BSS,
                                                                 base + 2 * BSS, base, ws, 0);
        k_terms<<<dim3(S, 9, BB), dim3(256), 0, stream>>>(be, bb, cb, eb, ee, ce, sp, gb, ge,
                                                          edge, chart, ws, base);
    }
}